// Round 2
// baseline (1940.492 us; speedup 1.0000x reference)
//
#include <hip/hip_runtime.h>
#include <hip/hip_bf16.h>
#include <math.h>

#define NNN 32768
#define CCH 256
#define GGG 64
#define NTOK (4*NNN)

typedef unsigned short u16;
typedef unsigned int u32;
typedef __attribute__((ext_vector_type(4))) u32 u32x4;
typedef __attribute__((ext_vector_type(2))) u32 u32x2;
typedef __attribute__((ext_vector_type(8))) short bh8;
typedef __attribute__((ext_vector_type(4))) float f32x4;

__device__ __forceinline__ float b2f(u16 s){ union{u32 u; float f;} c; c.u=((u32)s)<<16; return c.f; }
__device__ __forceinline__ u16 f2b(float f){ union{float f; u32 u;} c; c.f=f; u32 r=c.u+0x7fffu+((c.u>>16)&1u); return (u16)(r>>16); }
__device__ __forceinline__ void up2(u32 u, float&a, float&b){ union{u32 u; float f;} x,y; x.u=u<<16; y.u=u&0xffff0000u; a=x.f; b=y.f; }
__device__ __forceinline__ float gelu(float v){
  float t = v*(0.7978845608f + 0.0356774081f*v*v);
  return v / (1.0f + __expf(-2.0f*t));
}
__device__ __forceinline__ f32x4 MFMA(bh8 a, bh8 b, f32x4 c){ return __builtin_amdgcn_mfma_f32_16x16x32_bf16(a,b,c,0,0,0); }
__device__ __forceinline__ void ld32(const u16* p, float* d){
#pragma unroll
  for (int i=0;i<4;i++){
    u32x4 q = *(const u32x4*)(p + i*8);
    up2(q[0],d[i*8+0],d[i*8+1]); up2(q[1],d[i*8+2],d[i*8+3]);
    up2(q[2],d[i*8+4],d[i*8+5]); up2(q[3],d[i*8+6],d[i*8+7]);
  }
}

// ---------------- kconv: fp32 weights -> bf16 in ws ----------------
// dst layout (elements): Wfxc@0, Wxc@65536, Woutc@131072, Wm1c@196608, Wm2c@458752 (total 720896)
__global__ __launch_bounds__(256) void kconv(const float* __restrict__ Wfx, const float* __restrict__ Wx,
    const float* __restrict__ Wout, const float* __restrict__ Wm1, const float* __restrict__ Wm2,
    u16* __restrict__ dst)
{
  int vi = (blockIdx.x*256 + threadIdx.x)*4;
  const float* s; int off;
  if      (vi < 65536) { s=Wfx;  off=vi; }
  else if (vi < 131072){ s=Wx;   off=vi-65536; }
  else if (vi < 196608){ s=Wout; off=vi-131072; }
  else if (vi < 458752){ s=Wm1;  off=vi-196608; }
  else                 { s=Wm2;  off=vi-458752; }
  f32x4 v = *(const f32x4*)(s+off);
  u32x2 p; p[0]=(u32)f2b(v[0])|((u32)f2b(v[1])<<16); p[1]=(u32)f2b(v[2])|((u32)f2b(v[3])<<16);
  *(u32x2*)(dst+vi) = p;
}

// ---------------- K0: ln1(x) -> x1 (bf16, in d_out scratch), sb = MLP(pos) ----------------
__global__ __launch_bounds__(256) void k0(const float* __restrict__ x, const float* __restrict__ pos,
    const float* __restrict__ ln1g, const float* __restrict__ ln1b,
    const float* __restrict__ Wsb1, const float* __restrict__ bsb1,
    const float* __restrict__ Wsb2, const float* __restrict__ bsb2,
    const float* __restrict__ Wsb3, const float* __restrict__ bsb3,
    u16* __restrict__ x1, u16* __restrict__ sb)
{
  __shared__ float w1[64][5];
  __shared__ float w2[64][65];
  __shared__ float w3[64][65];
  __shared__ float hb1[4][64];
  __shared__ float hb2[4][64];
  int t = threadIdx.x;
  for (int i=t;i<256;i+=256) w1[i>>2][i&3] = Wsb1[i];
  for (int i=t;i<4096;i+=256){ w2[i>>6][i&63]=Wsb2[i]; w3[i>>6][i&63]=Wsb3[i]; }
  __syncthreads();
  int lane=t&63, w=t>>6;
  float g4[4], b4[4];
#pragma unroll
  for (int j=0;j<4;j++){ g4[j]=ln1g[lane*4+j]; b4[j]=ln1b[lane*4+j]; }
  float bs1=bsb1[lane], bs2=bsb2[lane], bs3=bsb3[lane];
  for (int it=0; it<64; ++it){
    int tok = blockIdx.x*256 + w*64 + it;
    f32x4 xv = *(const f32x4*)(x + (size_t)tok*CCH + lane*4);
    float v0=xv[0],v1=xv[1],v2=xv[2],v3=xv[3];
    float s=v0+v1+v2+v3, ss=v0*v0+v1*v1+v2*v2+v3*v3;
#pragma unroll
    for (int o=32;o;o>>=1){ s+=__shfl_xor(s,o); ss+=__shfl_xor(ss,o); }
    float mean=s*(1.0f/256.0f), var=ss*(1.0f/256.0f)-mean*mean;
    float rs=rsqrtf(var+1e-5f);
    u32x2 pv;
    pv[0]=(u32)f2b((v0-mean)*rs*g4[0]+b4[0]) | ((u32)f2b((v1-mean)*rs*g4[1]+b4[1])<<16);
    pv[1]=(u32)f2b((v2-mean)*rs*g4[2]+b4[2]) | ((u32)f2b((v3-mean)*rs*g4[3]+b4[3])<<16);
    *(u32x2*)(x1 + (size_t)tok*CCH + lane*4) = pv;
    // spatial-bias MLP
    f32x4 pq = *(const f32x4*)(pos + (size_t)tok*4);
    float h1 = gelu(pq[0]*w1[lane][0]+pq[1]*w1[lane][1]+pq[2]*w1[lane][2]+pq[3]*w1[lane][3]+bs1);
    hb1[w][lane]=h1;
    float h2=bs2;
#pragma unroll 8
    for (int j=0;j<64;j++) h2 += hb1[w][j]*w2[lane][j];
    h2 = gelu(h2);
    hb2[w][lane]=h2;
    float h3=bs3;
#pragma unroll 8
    for (int j=0;j<64;j++) h3 += hb2[w][j]*w3[lane][j];
    sb[(size_t)tok*GGG + lane] = f2b(h3);
  }
}

// ---------------- K1: fxm[t][0:256]=x1@Wfx^T+bfx ; fxm[t][256:512]=x1@Wx^T+bx ----------------
__global__ __launch_bounds__(256) void k1(const u16* __restrict__ x1,
    const u16* __restrict__ Wfxc, const float* __restrict__ bfx,
    const u16* __restrict__ Wxc, const float* __restrict__ bx,
    u16* __restrict__ fxm)
{
  __shared__ char sm[32768];
  char* As = sm; char* Bs = sm + 16384;
  int t=threadIdx.x, lane=t&63, w=t>>6;
  int wm=w>>1, wn=w&1;
  int m0 = blockIdx.x*128;
  int y = blockIdx.y;
  const u16* Wsel = (y<2)? (Wfxc + (size_t)y*128*256) : (Wxc + (size_t)(y-2)*128*256);
  const float* bsel = (y<2)? (bfx + y*128) : (bx + (y-2)*128);
  f32x4 acc[4][4];
#pragma unroll
  for (int i=0;i<4;i++)
#pragma unroll
  for (int j=0;j<4;j++){ f32x4 z={0.f,0.f,0.f,0.f}; acc[i][j]=z; }
  for (int kt=0; kt<4; ++kt){
    int k0 = kt*64;
#pragma unroll
    for (int c=0;c<4;c++){
      int q=(c*256+t)*16; int row=q>>7; int p=q&127;
      u32x4 va = *(const u32x4*)((const char*)x1 + (size_t)(m0+row)*512 + k0*2 + p);
      *(u32x4*)(As + (q ^ ((row&7)<<4))) = va;
      u32x4 vb = *(const u32x4*)((const char*)Wsel + (size_t)row*512 + k0*2 + p);
      *(u32x4*)(Bs + (q ^ ((row&7)<<4))) = vb;
    }
    __syncthreads();
#pragma unroll
    for (int kk=0;kk<2;kk++){
      int kb = kk*64 + (lane>>4)*16;
      bh8 a[4], b[4];
#pragma unroll
      for (int mf=0;mf<4;mf++){
        int row = wm*64 + mf*16 + (lane&15);
        a[mf] = *(const bh8*)(As + ((row*128 + kb) ^ ((row&7)<<4)));
      }
#pragma unroll
      for (int nf=0;nf<4;nf++){
        int row = wn*64 + nf*16 + (lane&15);
        b[nf] = *(const bh8*)(Bs + ((row*128 + kb) ^ ((row&7)<<4)));
      }
#pragma unroll
      for (int mf=0;mf<4;mf++)
#pragma unroll
      for (int nf=0;nf<4;nf++) acc[mf][nf] = MFMA(a[mf], b[nf], acc[mf][nf]);
    }
    __syncthreads();
  }
#pragma unroll
  for (int nf=0;nf<4;nf++){
    int cb = wn*64 + nf*16 + (lane&15);
    float bias = bsel[cb];
#pragma unroll
    for (int mf=0;mf<4;mf++)
#pragma unroll
    for (int j=0;j<4;j++){
      int row = m0 + wm*64 + mf*16 + (lane>>4)*4 + j;
      fxm[(size_t)row*512 + y*128 + cb] = f2b(acc[mf][nf][j] + bias);
    }
  }
}

// ---------------- K2: slice logits -> softmax sw ; accumulate snorm & stok ----------------
__global__ __launch_bounds__(512) void k2(const u16* __restrict__ fxm, const u16* __restrict__ sb,
    const float* __restrict__ Wsl, const float* __restrict__ bsl_, const float* __restrict__ temp,
    u16* __restrict__ swp, float* __restrict__ stok, float* __restrict__ snorm)
{
  int lane = threadIdx.x & 63, h = threadIdx.x >> 6;
  int b = blockIdx.y;
  int t0 = blockIdx.x * 128;
  float wsl[32];
#pragma unroll
  for (int i=0;i<8;i++){
    f32x4 v = *(const f32x4*)(Wsl + lane*32 + i*4);
    wsl[i*4]=v[0]; wsl[i*4+1]=v[1]; wsl[i*4+2]=v[2]; wsl[i*4+3]=v[3];
  }
  float bslv = bsl_[lane];
  float tv = fmaxf(temp[h], 1e-4f);
  float itv = 1.0f / tv;
  float acc[32];
#pragma unroll
  for (int i=0;i<32;i++) acc[i]=0.f;
  float sn = 0.f;
  for (int tt=0; tt<128; ++tt){
    int n = t0 + tt;
    size_t gtok = (size_t)b*NNN + n;
    float xm[32];
    ld32(fxm + gtok*512 + 256 + h*32, xm);
    float lg = bslv;
#pragma unroll
    for (int i=0;i<32;i++) lg += xm[i]*wsl[i];
    lg = lg*itv + 0.1f*b2f(sb[gtok*GGG + lane]);
    float mx = lg;
#pragma unroll
    for (int o=32;o;o>>=1) mx = fmaxf(mx, __shfl_xor(mx,o));
    float e = __expf(lg - mx);
    float es = e;
#pragma unroll
    for (int o=32;o;o>>=1) es += __shfl_xor(es,o);
    float swv = e / es;
    swp[((size_t)(b*8+h)*NNN + n)*GGG + lane] = f2b(swv);
    sn += swv;
    float fx[32];
    ld32(fxm + gtok*512 + h*32, fx);
#pragma unroll
    for (int i=0;i<32;i++) acc[i] += swv*fx[i];
  }
  float* sp = stok + ((size_t)(b*8+h)*GGG + lane)*32;
#pragma unroll
  for (int i=0;i<32;i++) atomicAdd(sp+i, acc[i]);
  atomicAdd(snorm + (b*8+h)*GGG + lane, sn);
}

// ---------------- K4: slice-token attention; o stored transposed [b][h][d][g] ----------------
__global__ __launch_bounds__(256) void k4(const float* __restrict__ stok, const float* __restrict__ snorm,
    const float* __restrict__ Wq, const float* __restrict__ Wk, const float* __restrict__ Wv,
    const float* __restrict__ asc, const float* __restrict__ srs, u16* __restrict__ ot)
{
  __shared__ float sts[64][33], kvs[64][33], qs[64][33], ks[64][33], vs[64][33];
  __shared__ float wq[32][33], wk[32][33], wv[32][33];
  int h = blockIdx.x, b = blockIdx.y, t = threadIdx.x;
  for (int i=t;i<1024;i+=256){ wq[i>>5][i&31]=Wq[i]; wk[i>>5][i&31]=Wk[i]; wv[i>>5][i&31]=Wv[i]; }
  for (int i=t;i<2048;i+=256){
    int g=i>>5, d=i&31;
    sts[g][d] = stok[((size_t)(b*8+h)*64+g)*32+d] / (snorm[(b*8+h)*64+g]+1e-5f);
    float s=0.f;
    for (int hh=0; hh<8; hh++)
      s += stok[((size_t)(b*8+hh)*64+g)*32+d] / (snorm[(b*8+hh)*64+g]+1e-5f);
    kvs[g][d] = s*0.125f;
  }
  __syncthreads();
  for (int i=t;i<2048;i+=256){
    int g=i>>5, d=i&31;
    float q=0.f,k=0.f,v=0.f;
    for (int dd=0;dd<32;dd++){ q+=sts[g][dd]*wq[d][dd]; k+=kvs[g][dd]*wk[d][dd]; v+=kvs[g][dd]*wv[d][dd]; }
    qs[g][d]=q; ks[g][d]=k; vs[g][d]=v;
  }
  __syncthreads();
  if (t<128){
    int g=t&63;
    float s=0.f;
    if (t<64){
      for (int d=0;d<32;d++) s+=qs[g][d]*qs[g][d];
      float inv=1.0f/fmaxf(sqrtf(s),1e-12f);
      for (int d=0;d<32;d++) qs[g][d]*=inv;
    } else {
      for (int d=0;d<32;d++) s+=ks[g][d]*ks[g][d];
      float inv=1.0f/fmaxf(sqrtf(s),1e-12f);
      for (int d=0;d<32;d++) ks[g][d]*=inv;
    }
  }
  __syncthreads();
  if (t<64){
    int g=t;
    float sc=asc[h], sv=srs[0];
    float mx=-1e30f;
    for (int gp=0;gp<64;gp++){
      float dt=0.f;
      for (int d=0;d<32;d++) dt+=qs[g][d]*ks[gp][d];
      mx = fmaxf(mx, dt*sc);
    }
    float esum=0.f; float orow[32];
#pragma unroll
    for (int d=0;d<32;d++) orow[d]=0.f;
    for (int gp=0;gp<64;gp++){
      float dt=0.f;
      for (int d=0;d<32;d++) dt+=qs[g][d]*ks[gp][d];
      float e=__expf(dt*sc-mx); esum+=e;
      for (int d=0;d<32;d++) orow[d]+=e*vs[gp][d];
    }
    float inv=1.0f/esum;
    for (int d=0;d<32;d++){
      float o = orow[d]*inv + sv*sts[g][d];
      ot[((size_t)(b*8+h)*32+d)*64+g] = f2b(o);
    }
  }
}

// ---------------- K5a: ox = sum_g o*sw ; a = ox@Wout^T+bout ; xnew = x + ln1p(a) ; xln2 = ln2(xnew) ----------------
__global__ __launch_bounds__(256) void k5a(const u16* __restrict__ swp, const u16* __restrict__ ot,
    const u16* __restrict__ Woutc, const float* __restrict__ bout,
    const float* __restrict__ x, const float* __restrict__ g1p, const float* __restrict__ b1p,
    const float* __restrict__ g2a, const float* __restrict__ b2a,
    u16* __restrict__ xnewg, u16* __restrict__ xln2g)
{
  __shared__ char arena[81920];
  char* SWs = arena;          // 32KB: sw tiles -> Wout tile -> a dump
  char* OTs = arena + 32768;  // 16KB: o tiles
  char* OXs = arena + 49152;  // 32KB: ox bf16 [64][256]
  int t=threadIdx.x, lane=t&63, w=t>>6;
  int tok0 = blockIdx.x*64;
  int b = tok0 >> 15;
  int n0 = tok0 & (NNN-1);
  f32x4 aox[2][4][2];
#pragma unroll
  for (int g_=0;g_<2;g_++)
#pragma unroll
  for (int i=0;i<4;i++)
#pragma unroll
  for (int j=0;j<2;j++){ f32x4 z={0.f,0.f,0.f,0.f}; aox[g_][i][j]=z; }
#pragma unroll
  for (int grp=0; grp<2; ++grp){
#pragma unroll
    for (int c=0;c<8;c++){
      int q=(c*256+t)*16;
      int h4=q>>13; int p=q&8191; int row=p>>7; int pr=p&127;
      u32x4 v = *(const u32x4*)((const char*)swp + ((size_t)((b*8+grp*4+h4)*NNN + n0 + row))*128 + pr);
      *(u32x4*)(SWs + (q ^ ((row&7)<<4))) = v;
    }
#pragma unroll
    for (int c=0;c<4;c++){
      int q=(c*256+t)*16; int row=q>>7;
      u32x4 v = *(const u32x4*)((const char*)ot + (size_t)(b*8+grp*4)*4096 + q);
      *(u32x4*)(OTs + (q ^ ((row&7)<<4))) = v;
    }
    __syncthreads();
#pragma unroll
    for (int kk=0;kk<2;kk++){
      int kb = kk*64 + (lane>>4)*16;
      bh8 a[4], bb[2];
#pragma unroll
      for (int mf=0;mf<4;mf++){
        int row = mf*16+(lane&15);
        a[mf] = *(const bh8*)(SWs + w*8192 + ((row*128+kb) ^ ((row&7)<<4)));
      }
#pragma unroll
      for (int nf=0;nf<2;nf++){
        int row = nf*16+(lane&15);
        bb[nf] = *(const bh8*)(OTs + w*4096 + ((row*128+kb) ^ ((row&7)<<4)));
      }
#pragma unroll
      for (int mf=0;mf<4;mf++)
#pragma unroll
      for (int nf=0;nf<2;nf++) aox[grp][mf][nf] = MFMA(a[mf], bb[nf], aox[grp][mf][nf]);
    }
    __syncthreads();
  }
#pragma unroll
  for (int grp=0;grp<2;grp++)
#pragma unroll
  for (int mf=0;mf<4;mf++)
#pragma unroll
  for (int nf=0;nf<2;nf++)
#pragma unroll
  for (int j=0;j<4;j++){
    int row = mf*16 + (lane>>4)*4 + j;
    int col = (grp*4+w)*32 + nf*16 + (lane&15);
    *(u16*)(OXs + ((row*512 + col*2) ^ ((row&7)<<4))) = f2b(aox[grp][mf][nf][j]);
  }
  __syncthreads();
  f32x4 aa[4][4];
#pragma unroll
  for (int i=0;i<4;i++)
#pragma unroll
  for (int j=0;j<4;j++){ f32x4 z={0.f,0.f,0.f,0.f}; aa[i][j]=z; }
  for (int kc=0;kc<4;kc++){
#pragma unroll
    for (int c=0;c<8;c++){
      int q=(c*256+t)*16; int row=q>>7; int p=q&127;
      u32x4 v = *(const u32x4*)((const char*)Woutc + (size_t)row*512 + kc*128 + p);
      *(u32x4*)(SWs + (q ^ ((row&7)<<4))) = v;
    }
    __syncthreads();
#pragma unroll
    for (int kk=0;kk<2;kk++){
      int kbA = kc*128 + kk*64 + (lane>>4)*16;
      int kbW = kk*64 + (lane>>4)*16;
      bh8 a[4], bb[4];
#pragma unroll
      for (int mf=0;mf<4;mf++){
        int row = mf*16+(lane&15);
        a[mf] = *(const bh8*)(OXs + ((row*512+kbA) ^ ((row&7)<<4)));
      }
#pragma unroll
      for (int nf=0;nf<4;nf++){
        int row = w*64+nf*16+(lane&15);
        bb[nf] = *(const bh8*)(SWs + ((row*128+kbW) ^ ((row&7)<<4)));
      }
#pragma unroll
      for (int mf=0;mf<4;mf++)
#pragma unroll
      for (int nf=0;nf<4;nf++) aa[mf][nf]=MFMA(a[mf],bb[nf],aa[mf][nf]);
    }
    __syncthreads();
  }
#pragma unroll
  for (int nf=0;nf<4;nf++){
    int cb = w*64+nf*16+(lane&15);
    float bv = bout[cb];
#pragma unroll
    for (int mf=0;mf<4;mf++)
#pragma unroll
    for (int j=0;j<4;j++){
      int row = mf*16+(lane>>4)*4+j;
      *(u16*)(SWs + ((row*512+cb*2) ^ ((row&7)<<4))) = f2b(aa[mf][nf][j]+bv);
    }
  }
  __syncthreads();
  float g1v[4],b1v[4],g2v[4],b2v[4];
#pragma unroll
  for (int j=0;j<4;j++){ g1v[j]=g1p[lane*4+j]; b1v[j]=b1p[lane*4+j]; g2v[j]=g2a[lane*4+j]; b2v[j]=b2a[lane*4+j]; }
  for (int i=0;i<16;i++){
    int r = w*16+i;
    u32x2 av = *(const u32x2*)(SWs + ((r*512 + lane*8) ^ ((r&7)<<4)));
    float a0,a1,a2,a3; up2(av[0],a0,a1); up2(av[1],a2,a3);
    float s=a0+a1+a2+a3, ss=a0*a0+a1*a1+a2*a2+a3*a3;
#pragma unroll
    for (int o=32;o;o>>=1){ s+=__shfl_xor(s,o); ss+=__shfl_xor(ss,o); }
    float mean=s*(1.f/256.f), var=ss*(1.f/256.f)-mean*mean, rs=rsqrtf(var+1e-5f);
    f32x4 xv = *(const f32x4*)(x + (size_t)(tok0+r)*256 + lane*4);
    float e0 = xv[0] + (a0-mean)*rs*g1v[0]+b1v[0];
    float e1 = xv[1] + (a1-mean)*rs*g1v[1]+b1v[1];
    float e2 = xv[2] + (a2-mean)*rs*g1v[2]+b1v[2];
    float e3 = xv[3] + (a3-mean)*rs*g1v[3]+b1v[3];
    float s2=e0+e1+e2+e3, ss2=e0*e0+e1*e1+e2*e2+e3*e3;
#pragma unroll
    for (int o=32;o;o>>=1){ s2+=__shfl_xor(s2,o); ss2+=__shfl_xor(ss2,o); }
    float mean2=s2*(1.f/256.f), var2=ss2*(1.f/256.f)-mean2*mean2, rs2=rsqrtf(var2+1e-5f);
    u32x2 pn, pl;
    pn[0]=(u32)f2b(e0)|((u32)f2b(e1)<<16); pn[1]=(u32)f2b(e2)|((u32)f2b(e3)<<16);
    *(u32x2*)(xnewg + (size_t)(tok0+r)*256 + lane*4) = pn;
    float l0=(e0-mean2)*rs2*g2v[0]+b2v[0];
    float l1=(e1-mean2)*rs2*g2v[1]+b2v[1];
    float l2=(e2-mean2)*rs2*g2v[2]+b2v[2];
    float l3=(e3-mean2)*rs2*g2v[3]+b2v[3];
    pl[0]=(u32)f2b(l0)|((u32)f2b(l1)<<16); pl[1]=(u32)f2b(l2)|((u32)f2b(l3)<<16);
    *(u32x2*)(xln2g + (size_t)(tok0+r)*256 + lane*4) = pl;
  }
}

// ---------------- K5b: m = gelu(xln2@Wm1^T+bm1)@Wm2^T+bm2 ; x2 = xnew + ln2p(m) ; colsum ----------------
__global__ __launch_bounds__(256) void k5b(const u16* __restrict__ xln2g, const u16* __restrict__ xnewg,
    const u16* __restrict__ Wm1c, const float* __restrict__ bm1,
    const u16* __restrict__ Wm2c, const float* __restrict__ bm2,
    const float* __restrict__ g2p, const float* __restrict__ b2p,
    u16* __restrict__ x2g, float* __restrict__ colsum)
{
  __shared__ char arena[70656];
  char* XT = arena;            // 32KB
  char* W1 = arena + 32768;    // 16KB
  char* W2 = arena + 49152;    // 16KB
  char* HB = arena + 65536;    // 4KB
  float* CS = (float*)(arena + 69632); // 1KB
  int t=threadIdx.x, lane=t&63, w=t>>6;
  int tok0=blockIdx.x*64, b=tok0>>15;
#pragma unroll
  for (int c=0;c<8;c++){
    int q=(c*256+t)*16; int row=q>>9;
    u32x4 v = *(const u32x4*)((const char*)xln2g + (size_t)tok0*512 + q);
    *(u32x4*)(XT + (q ^ ((row&7)<<4))) = v;
  }
  f32x4 macc[4][4];
#pragma unroll
  for (int i=0;i<4;i++)
#pragma unroll
  for (int j=0;j<4;j++){ f32x4 z={0.f,0.f,0.f,0.f}; macc[i][j]=z; }
  for (int it=0; it<32; ++it){
    int hc0 = it*32;
    __syncthreads();
#pragma unroll
    for (int c=0;c<4;c++){
      int q=(c*256+t)*16; int row=q>>9;
      u32x4 v = *(const u32x4*)((const char*)Wm1c + (size_t)hc0*512 + q);
      *(u32x4*)(W1 + (q ^ ((row&7)<<4))) = v;
    }
#pragma unroll
    for (int c=0;c<4;c++){
      int q=(c*256+t)*16; int n=q>>6; int p=q&63;
      u32x4 v = *(const u32x4*)((const char*)Wm2c + (size_t)n*2048 + hc0*2 + p);
      *(u32x4*)(W2 + (q ^ ((n&3)<<4))) = v;
    }
    __syncthreads();
    f32x4 hacc[2];
    { f32x4 z={0.f,0.f,0.f,0.f}; hacc[0]=z; hacc[1]=z; }
#pragma unroll
    for (int kk=0;kk<8;kk++){
      int kb = kk*64 + (lane>>4)*16;
      int rowa = w*16 + (lane&15);
      bh8 a = *(const bh8*)(XT + ((rowa*512+kb) ^ ((rowa&7)<<4)));
#pragma unroll
      for (int nf=0;nf<2;nf++){
        int rn = nf*16+(lane&15);
        bh8 bb = *(const bh8*)(W1 + ((rn*512+kb) ^ ((rn&7)<<4)));
        hacc[nf] = MFMA(a, bb, hacc[nf]);
      }
    }
#pragma unroll
    for (int nf=0;nf<2;nf++){
      int col = nf*16+(lane&15);
      float bmv = bm1[hc0+col];
#pragma unroll
      for (int j=0;j<4;j++){
        int row = w*16 + (lane>>4)*4 + j;
        float hv = gelu(hacc[nf][j]+bmv);
        *(u16*)(HB + ((row*64+col*2) ^ ((row&3)<<4))) = f2b(hv);
      }
    }
    __syncthreads();
    {
      int kb2 = (lane>>4)*16;
      bh8 a2[4], b2v_[4];
#pragma unroll
      for (int mf=0;mf<4;mf++){
        int row = mf*16+(lane&15);
        a2[mf] = *(const bh8*)(HB + ((row*64+kb2) ^ ((row&3)<<4)));
      }
#pragma unroll
      for (int nf=0;nf<4;nf++){
        int rn = w*64+nf*16+(lane&15);
        b2v_[nf] = *(const bh8*)(W2 + ((rn*64+kb2) ^ ((rn&3)<<4)));
      }
#pragma unroll
      for (int mf=0;mf<4;mf++)
#pragma unroll
      for (int nf=0;nf<4;nf++) macc[mf][nf]=MFMA(a2[mf],b2v_[nf],macc[mf][nf]);
    }
  }
  __syncthreads();
  char* MD = arena + 32768;  // 32KB m dump (over W1+W2)
#pragma unroll
  for (int nf=0;nf<4;nf++){
    int cb = w*64+nf*16+(lane&15);
    float bv = bm2[cb];
#pragma unroll
    for (int mf=0;mf<4;mf++)
#pragma unroll
    for (int j=0;j<4;j++){
      int row = mf*16+(lane>>4)*4+j;
      *(u16*)(MD + ((row*512+cb*2) ^ ((row&7)<<4))) = f2b(macc[mf][nf][j]+bv);
    }
  }
  CS[t] = 0.f;
  __syncthreads();
  float g2v[4],b2v[4];
#pragma unroll
  for (int j=0;j<4;j++){ g2v[j]=g2p[lane*4+j]; b2v[j]=b2p[lane*4+j]; }
  float cs4[4]={0.f,0.f,0.f,0.f};
  for (int i=0;i<16;i++){
    int r=w*16+i;
    u32x2 mv = *(const u32x2*)(MD + ((r*512+lane*8) ^ ((r&7)<<4)));
    float m0,m1,m2,m3; up2(mv[0],m0,m1); up2(mv[1],m2,m3);
    float s=m0+m1+m2+m3, ss=m0*m0+m1*m1+m2*m2+m3*m3;
#pragma unroll
    for (int o=32;o;o>>=1){ s+=__shfl_xor(s,o); ss+=__shfl_xor(ss,o); }
    float mean=s*(1.f/256.f), var=ss*(1.f/256.f)-mean*mean, rs=rsqrtf(var+1e-5f);
    u32x2 xv = *(const u32x2*)(xnewg + (size_t)(tok0+r)*256 + lane*4);
    float x0,x1,x2,x3; up2(xv[0],x0,x1); up2(xv[1],x2,x3);
    float v0 = x0 + (m0-mean)*rs*g2v[0]+b2v[0];
    float v1 = x1 + (m1-mean)*rs*g2v[1]+b2v[1];
    float v2 = x2 + (m2-mean)*rs*g2v[2]+b2v[2];
    float v3 = x3 + (m3-mean)*rs*g2v[3]+b2v[3];
    cs4[0]+=v0; cs4[1]+=v1; cs4[2]+=v2; cs4[3]+=v3;
    u32x2 pv;
    pv[0]=(u32)f2b(v0)|((u32)f2b(v1)<<16); pv[1]=(u32)f2b(v2)|((u32)f2b(v3)<<16);
    *(u32x2*)(x2g + (size_t)(tok0+r)*256 + lane*4) = pv;
  }
#pragma unroll
  for (int j=0;j<4;j++) atomicAdd(&CS[lane*4+j], cs4[j]);
  __syncthreads();
  atomicAdd(&colsum[b*256+t], CS[t]);
}

// ---------------- K6: SE gate ----------------
__global__ __launch_bounds__(256) void k6(const float* __restrict__ colsum,
    const float* __restrict__ Wse1, const float* __restrict__ bse1,
    const float* __restrict__ Wse2, const float* __restrict__ bse2,
    float* __restrict__ sep)
{
  __shared__ float mean[256];
  __shared__ float h1[64];
  int b=blockIdx.x, t=threadIdx.x;
  mean[t] = colsum[b*256+t]*(1.0f/32768.0f);
  __syncthreads();
  if (t<64){
    float s=bse1[t];
    for (int c=0;c<256;c++) s += mean[c]*Wse1[t*256+c];
    h1[t]=gelu(s);
  }
  __syncthreads();
  float s=bse2[t];
  for (int j=0;j<64;j++) s += h1[j]*Wse2[t*64+j];
  sep[b*256+t] = 1.0f + s;
}

// ---------------- K7: out = x2 * (1 + se), fp32 output ----------------
__global__ __launch_bounds__(256) void k7(const u16* __restrict__ x2g, const float* __restrict__ sep,
    float* __restrict__ out)
{
  size_t e0 = ((size_t)blockIdx.x*256 + threadIdx.x)*8;
  int c0 = (int)(e0 & 255);
  int b = (int)(e0 >> 23);
  const float* sp = sep + b*256 + c0;
  u32x4 v = *(const u32x4*)(x2g + e0);
  f32x4 o0, o1;
#pragma unroll
  for (int k=0;k<4;k++){
    float lo,hi; up2(v[k],lo,hi);
    float r0 = lo*sp[k*2], r1 = hi*sp[k*2+1];
    if (k<2){ o0[k*2]=r0; o0[k*2+1]=r1; } else { o1[(k-2)*2]=r0; o1[(k-2)*2+1]=r1; }
  }
  *(f32x4*)(out+e0)=o0; *(f32x4*)(out+e0+4)=o1;
}

// ---------------- launch ----------------
#define OFF_SW   ((size_t)0)
#define SZ_SW    ((size_t)134217728)
#define OFF_FXM  (OFF_SW + SZ_SW)
#define SZ_FXM   ((size_t)134217728)
#define OFF_SB   (OFF_FXM + SZ_FXM)
#define SZ_SB    ((size_t)16777216)
#define OFF_STOK (OFF_SB + SZ_SB)
#define SZ_STOK  ((size_t)262144)
#define OFF_SNORM (OFF_STOK + SZ_STOK)
#define SZ_SNORM ((size_t)8192)
#define OFF_CS   (OFF_SNORM + SZ_SNORM)
#define SZ_CS    ((size_t)4096)
#define OFF_OT   (OFF_CS + SZ_CS)
#define SZ_OT    ((size_t)131072)
#define OFF_SEP  (OFF_OT + SZ_OT)
#define SZ_SEP   ((size_t)4096)
#define OFF_WC   (OFF_SEP + SZ_SEP)
#define SZ_WC    ((size_t)1441792)
#define WS_NEED  (OFF_WC + SZ_WC)

extern "C" void kernel_launch(void* const* d_in, const int* in_sizes, int n_in,
                              void* d_out, int out_size, void* d_ws, size_t ws_size,
                              hipStream_t stream)
{
  const float* x    = (const float*)d_in[0];
  const float* pos  = (const float*)d_in[1];
  const float* ln1g = (const float*)d_in[2];
  const float* ln1b = (const float*)d_in[3];
  const float* ln1pg= (const float*)d_in[4];
  const float* ln1pb= (const float*)d_in[5];
  const float* ln2g = (const float*)d_in[6];
  const float* ln2b = (const float*)d_in[7];
  const float* ln2pg= (const float*)d_in[8];
  const float* ln2pb= (const float*)d_in[9];
  const float* Wx   = (const float*)d_in[10];
  const float* bx   = (const float*)d_in[11];
  const float* Wfx  = (const float*)d_in[12];
  const float* bfx  = (const float*)d_in[13];
  const float* Wsl  = (const float*)d_in[14];
  const float* bsl  = (const float*)d_in[15];
  const float* temp = (const float*)d_in[16];
  const float* Wq   = (const float*)d_in[17];
  const float* Wk   = (const float*)d_in[18];
  const float* Wv   = (const float*)d_in[19];
  const float* asc  = (const float*)d_in[20];
  const float* srs  = (const float*)d_in[21];
  const float* Wout = (const float*)d_in[22];
  const float* bout = (const float*)d_in[23];
  const float* Wm1  = (const float*)d_in[24];
  const float* bm1  = (const float*)d_in[25];
  const float* Wm2  = (const float*)d_in[26];
  const float* bm2  = (const float*)d_in[27];
  const float* Wsb1 = (const float*)d_in[28];
  const float* bsb1 = (const float*)d_in[29];
  const float* Wsb2 = (const float*)d_in[30];
  const float* bsb2 = (const float*)d_in[31];
  const float* Wsb3 = (const float*)d_in[32];
  const float* bsb3 = (const float*)d_in[33];
  const float* Wse1 = (const float*)d_in[34];
  const float* bse1 = (const float*)d_in[35];
  const float* Wse2 = (const float*)d_in[36];
  const float* bse2 = (const float*)d_in[37];
  char* ws = (char*)d_ws;
  if (ws_size < WS_NEED) return;  // insufficient scratch; avoid corruption

  u16* x1    = (u16*)d_out;                 // x1 (bf16) scratch lives in d_out until K7 overwrites
  u16* sb    = (u16*)(ws + OFF_SB);
  u16* fxm   = (u16*)(ws + OFF_FXM);
  u16* swp   = (u16*)(ws + OFF_SW);
  float* stok  = (float*)(ws + OFF_STOK);
  float* snorm = (float*)(ws + OFF_SNORM);
  float* colsum= (float*)(ws + OFF_CS);
  u16* ot    = (u16*)(ws + OFF_OT);
  float* sep = (float*)(ws + OFF_SEP);
  u16* wc    = (u16*)(ws + OFF_WC);
  u16* Wfxc  = wc;
  u16* Wxc   = wc + 65536;
  u16* Woutc = wc + 131072;
  u16* Wm1c  = wc + 196608;
  u16* Wm2c  = wc + 458752;
  u16* xnewg = (u16*)(ws + OFF_FXM);                              // reuse fxm (dead after k2)
  u16* xln2g = (u16*)(ws + OFF_FXM + (size_t)NTOK*CCH*2);
  u16* x2g   = (u16*)(ws + OFF_SW);                               // reuse sw (dead after k5a)

  hipMemsetAsync(ws + OFF_STOK, 0, SZ_STOK+SZ_SNORM+SZ_CS, stream);
  kconv<<<dim3(704), dim3(256), 0, stream>>>(Wfx, Wx, Wout, Wm1, Wm2, wc);
  k0<<<dim3(512), dim3(256), 0, stream>>>(x,pos,ln1g,ln1b,Wsb1,bsb1,Wsb2,bsb2,Wsb3,bsb3,x1,sb);
  k1<<<dim3(1024,4), dim3(256), 0, stream>>>(x1, Wfxc,bfx, Wxc,bx, fxm);
  k2<<<dim3(256,4), dim3(512), 0, stream>>>(fxm, sb, Wsl, bsl, temp, swp, stok, snorm);
  k4<<<dim3(8,4), dim3(256), 0, stream>>>(stok, snorm, Wq,Wk,Wv, asc, srs, ot);
  k5a<<<dim3(2048), dim3(256), 0, stream>>>(swp, ot, Woutc, bout, x, ln1pg, ln1pb, ln2g, ln2b, xnewg, xln2g);
  k5b<<<dim3(2048), dim3(256), 0, stream>>>(xln2g, xnewg, Wm1c,bm1,Wm2c,bm2, ln2pg, ln2pb, x2g, colsum);
  k6<<<dim3(4), dim3(256), 0, stream>>>(colsum, Wse1,bse1,Wse2,bse2, sep);
  k7<<<dim3(16384), dim3(256), 0, stream>>>(x2g, sep, (float*)d_out);
}